// Round 7
// baseline (42.435 us; speedup 1.0000x reference)
//
#include <hip/hip_runtime.h>
#include <math.h>

typedef __attribute__((ext_vector_type(8))) short bf16x8;
typedef __attribute__((ext_vector_type(4))) float f32x4;

// triangular x-pooling table WXT[n][x] (bf16 bits); conv ksize=12, stride=8, pad=3
struct alignas(16) WxTbl { unsigned short v[16 * 32]; };

static constexpr WxTbl gen_wx() {
    WxTbl t{};
    for (int n = 0; n < 16; ++n)
        for (int x = 0; x < 32; ++x) {
            float w = 0.0f;
            if (n < 4) {
                int kx = x - 8 * n + 3;
                if (kx >= 0 && kx < 12) {
                    float d = (float)kx - 5.5f; if (d < 0) d = -d;
                    w = 6.0f - d;               // unnormalized tri; scale cancels in l2norm
                }
            }
            t.v[n * 32 + x] = (unsigned short)(__builtin_bit_cast(unsigned int, w) >> 16);
        }
    return t;
}

__device__ const WxTbl WXT = gen_wx();

// separable gaussian table G[i] = exp(-(i-15.5)^2/1024), constexpr Taylor (arg in [-0.235,0])
struct alignas(16) GTbl { float v[32]; };
static constexpr GTbl gen_g() {
    GTbl t{};
    for (int i = 0; i < 32; ++i) {
        double x = -((i - 15.5) * (i - 15.5)) / 1024.0;
        double s = 1.0, term = 1.0;
        for (int k = 1; k < 16; ++k) { term *= x / k; s += term; }
        t.v[i] = (float)s;
    }
    return t;
}
__device__ const GTbl GT = gen_g();

#define R2S 36   // r2f row stride (floats)

__global__ __launch_bounds__(256) void sift_desc_kernel(
        const float* __restrict__ in, float* __restrict__ out) {
    __shared__ __align__(16) unsigned short ang[8192];  // [bin*32+y][x] bf16, 16 KB, LINEAR
    __shared__ __align__(16) float r2f[32 * R2S];       // [a*4+ox][y], f32
    __shared__ float scratch[6];

    const int b = blockIdx.x, tid = threadIdx.x;
    constexpr float EPS = 1e-10f;

    // zero-fill ang (scatter targets are data-dependent -> must precede barrier)
    {
        const float4 z = make_float4(0.f, 0.f, 0.f, 0.f);
        float4* az = reinterpret_cast<float4*>(ang);
        az[tid] = z; az[tid + 256] = z; az[tid + 512] = z; az[tid + 768] = z;
    }

    // ---- phase 0: gradients straight from global -> weighted mag -> octant scatter ----
    const int r  = tid >> 3;          // row 0..31
    const int sg = tid & 7;           // segment 0..7
    const int x0 = sg * 4;
    const float* gp = in + (size_t)b * 1024;
    const float4 cur = *reinterpret_cast<const float4*>(gp + r * 32 + x0);
    const int rup = (r > 0) ? r - 1 : 0, rdn = (r < 31) ? r + 1 : 31;
    const float4 up = *reinterpret_cast<const float4*>(gp + rup * 32 + x0);
    const float4 dn = *reinterpret_cast<const float4*>(gp + rdn * 32 + x0);
    const float gyw = GT.v[r];
    const float4 gxw4 = *reinterpret_cast<const float4*>(GT.v + x0);
    const float gxs[4] = {gxw4.x, gxw4.y, gxw4.z, gxw4.w};

    const float lfs = __shfl_up(cur.w, 1);
    const float rts = __shfl_down(cur.x, 1);
    const float lf = (sg == 0) ? cur.x : lfs;   // replicate-pad at x=0
    const float rt = (sg == 7) ? cur.w : rts;   // replicate-pad at x=31

    // u = 2*gx, v = 2*gy (0.5 folded into mag)
    const float uu[4] = {cur.y - lf, cur.z - cur.x, cur.w - cur.y, rt - cur.z};
    const float vv[4] = {dn.x - up.x, dn.y - up.y, dn.z - up.z, dn.w - up.w};

    __syncthreads();   // zero-fill visible before scatter

    {
        const int base2 = (r * 32 + x0) * 2;
        char* angb = reinterpret_cast<char*>(ang);
        #pragma unroll
        for (int i = 0; i < 4; ++i) {
            const float u = uu[i], v = vv[i];
            const float gw = gxs[i] * gyw;
            const float m2 = fmaf(u, u, v * v);
            const float mag = __builtin_amdgcn_sqrtf(fmaf(m2, 0.25f, EPS)) * gw;

            // octant-direct soft binning: bins are exactly pi/4 wide.
            const float gxe = u + 2e-10f;
            const float ax = fabsf(gxe), ay = fabsf(v);
            const float mx = fmaxf(ax, ay), mn = fminf(ax, ay);
            const float t = mn * __builtin_amdgcn_rcpf(fmaxf(mx, 1e-35f));
            const float s = t * t;
            float pl = fmaf(s, -0.01492400f, 0.06704059f);   // coeffs pre-scaled by 4/pi
            pl = fmaf(s, pl, -0.14824021f);
            pl = fmaf(s, pl, 0.24642768f);
            pl = fmaf(s, pl, -0.42350528f);
            pl = fmaf(s, pl, 1.27321059f);
            const float p = t * pl;                          // in-octant fraction [0,1]

            const int ssw = (ay > ax);
            const int sx  = (gxe < 0.0f);
            const int sy  = (v < 0.0f);
            const int bit0 = ssw ^ sx;
            const int oct  = ((sx << 1) | bit0) ^ (sy ? 7 : 0);   // = bin0
            const float par = (float)(bit0 ^ sy);                  // oct & 1
            const float w1 = fabsf(p - par);
            const float m1 = w1 * mag;
            const float m0 = mag - m1;

            const unsigned short h0 =
                (unsigned short)((__builtin_bit_cast(unsigned int, m0) + 0x8000u) >> 16);
            const unsigned short h1 =
                (unsigned short)((__builtin_bit_cast(unsigned int, m1) + 0x8000u) >> 16);
            *reinterpret_cast<unsigned short*>(angb + (oct << 11) + base2 + 2 * i) = h0;
            *reinterpret_cast<unsigned short*>(
                angb + ((((oct + 1) & 7) << 11) + base2 + 2 * i)) = h1;
        }
    }
    __syncthreads();

    // ---- GEMM1 (MFMA): x-pooling. A = ang (256x32), B^T = WXT (16x32) ----
    {
        const int l = tid & 63, w = tid >> 6, g = l >> 4, n = l & 15;
        const bf16x8 bfrag = *reinterpret_cast<const bf16x8*>(WXT.v + n * 32 + g * 8);
        const f32x4 zacc = {0.f, 0.f, 0.f, 0.f};
        #pragma unroll
        for (int tt = 0; tt < 4; ++tt) {
            const int T = w * 4 + tt;   // row tile 0..15
            const bf16x8 afrag = *reinterpret_cast<const bf16x8*>(
                ang + (T * 16 + n) * 32 + g * 8);
            const f32x4 acc = __builtin_amdgcn_mfma_f32_16x16x32_bf16(afrag, bfrag, zacc, 0, 0, 0);
            if (n < 4) {
                // C layout: row = T*16 + 4g + reg, col = n (=ox)
                const int row = T * 16 + 4 * g;
                const int a = row >> 5, y0 = row & 31;
                *reinterpret_cast<float4*>(r2f + (a * 4 + n) * R2S + y0) =
                    make_float4(acc[0], acc[1], acc[2], acc[3]);
            }
        }
    }
    __syncthreads();

    // ---- phase 2: y-pooling (VALU) ----
    float v = 0.0f;
    if (tid < 128) {
        const int a = tid >> 4, oy = (tid >> 2) & 3, ox = tid & 3;
        const float* rp = r2f + (a * 4 + ox) * R2S;
        const int y0 = oy * 8 - 3;
        #pragma unroll
        for (int k = 0; k < 12; ++k) {
            const float wk = 6.0f - fabsf((float)k - 5.5f);   // compile-time
            const int yy = y0 + k;
            const int yc = (yy < 0) ? 0 : ((yy > 31) ? 31 : yy);
            const float wv = (yy == yc) ? wk : 0.0f;
            v = fmaf(wv, rp[yc], v);
        }
    }

    // ---- norm chain: l2 -> clip(0,0.2) -> l2 -> l1 -> sqrt(+eps); 1 barrier each ----
    float red = v * v;
    #pragma unroll
    for (int off = 32; off; off >>= 1) red += __shfl_down(red, off);
    if ((tid & 63) == 0 && tid < 128) scratch[tid >> 6] = red;
    __syncthreads();
    float s2 = scratch[0] + scratch[1];
    v = v / fmaxf(__builtin_amdgcn_sqrtf(s2), 1e-12f);
    v = fminf(fmaxf(v, 0.0f), 0.2f);

    red = v * v;
    #pragma unroll
    for (int off = 32; off; off >>= 1) red += __shfl_down(red, off);
    if ((tid & 63) == 0 && tid < 128) scratch[2 + (tid >> 6)] = red;
    __syncthreads();
    float s2b = scratch[2] + scratch[3];
    v = v / fmaxf(__builtin_amdgcn_sqrtf(s2b), 1e-12f);

    red = v;
    #pragma unroll
    for (int off = 32; off; off >>= 1) red += __shfl_down(red, off);
    if ((tid & 63) == 0 && tid < 128) scratch[4 + (tid >> 6)] = red;
    __syncthreads();
    float s1 = scratch[4] + scratch[5];
    v = __builtin_amdgcn_sqrtf(v / fmaxf(s1, 1e-12f) + EPS);

    if (tid < 128) out[(size_t)b * 128 + tid] = v;
}

extern "C" void kernel_launch(void* const* d_in, const int* in_sizes, int n_in,
                              void* d_out, int out_size, void* d_ws, size_t ws_size,
                              hipStream_t stream) {
    const float* in = (const float*)d_in[0];
    float* out = (float*)d_out;
    const int batch = in_sizes[0] / 1024;   // 32*32 per patch
    sift_desc_kernel<<<batch, 256, 0, stream>>>(in, out);
}

// Round 8
// 42.082 us; speedup vs baseline: 1.0084x; 1.0084x over previous
//
#include <hip/hip_runtime.h>
#include <hip/hip_bf16.h>
#include <math.h>

typedef __attribute__((ext_vector_type(8))) short bf16x8;
typedef __attribute__((ext_vector_type(4))) float f32x4;

// triangular x-pooling table WXT[n][x] (bf16 bits); conv ksize=12, stride=8, pad=3
struct alignas(16) WxTbl { unsigned short v[16 * 32]; };

static constexpr WxTbl gen_wx() {
    WxTbl t{};
    for (int n = 0; n < 16; ++n)
        for (int x = 0; x < 32; ++x) {
            float w = 0.0f;
            if (n < 4) {
                int kx = x - 8 * n + 3;
                if (kx >= 0 && kx < 12) {
                    float d = (float)kx - 5.5f; if (d < 0) d = -d;
                    w = 6.0f - d;               // unnormalized tri; scale cancels in l2norm
                }
            }
            t.v[n * 32 + x] = (unsigned short)(__builtin_bit_cast(unsigned int, w) >> 16);
        }
    return t;
}

__device__ const WxTbl WXT = gen_wx();

// separable gaussian table G[i] = exp(-(i-15.5)^2/1024), constexpr Taylor
struct alignas(16) GTbl { float v[32]; };
static constexpr GTbl gen_g() {
    GTbl t{};
    for (int i = 0; i < 32; ++i) {
        double x = -((i - 15.5) * (i - 15.5)) / 1024.0;
        double s = 1.0, term = 1.0;
        for (int k = 1; k < 16; ++k) { term *= x / k; s += term; }
        t.v[i] = (float)s;
    }
    return t;
}
__device__ const GTbl GT = gen_g();

#define R2S 36   // r2f row stride (floats)

__global__ __launch_bounds__(256, 8) void sift_desc_kernel(
        const float* __restrict__ in, float* __restrict__ out) {
    // 16 KB. Phase A: ang[bin*32+y][x] bf16. Phase B: front 4.6 KB reused as f32 r2f.
    __shared__ __align__(16) unsigned short ang[8192];
    __shared__ float scratch[6];

    const int b = blockIdx.x, tid = threadIdx.x;
    constexpr float EPS = 1e-10f;

    // zero-fill ang
    {
        const float4 z = make_float4(0.f, 0.f, 0.f, 0.f);
        float4* az = reinterpret_cast<float4*>(ang);
        az[tid] = z; az[tid + 256] = z; az[tid + 512] = z; az[tid + 768] = z;
    }

    // ---- phase 0: gradients from global -> weighted mag -> octant scatter ----
    const int r  = tid >> 3;          // row 0..31
    const int sg = tid & 7;           // segment 0..7
    const int x0 = sg * 4;
    const float* gp = in + (size_t)b * 1024;
    const float4 cur = *reinterpret_cast<const float4*>(gp + r * 32 + x0);
    const int rup = (r > 0) ? r - 1 : 0, rdn = (r < 31) ? r + 1 : 31;
    const float4 up = *reinterpret_cast<const float4*>(gp + rup * 32 + x0);
    const float4 dn = *reinterpret_cast<const float4*>(gp + rdn * 32 + x0);
    const float gyw = GT.v[r];
    const float4 gxw4 = *reinterpret_cast<const float4*>(GT.v + x0);
    const float gxs[4] = {gxw4.x, gxw4.y, gxw4.z, gxw4.w};

    const float lfs = __shfl_up(cur.w, 1);
    const float rts = __shfl_down(cur.x, 1);
    const float lf = (sg == 0) ? cur.x : lfs;   // replicate-pad at x=0
    const float rt = (sg == 7) ? cur.w : rts;   // replicate-pad at x=31

    // u = 2*gx, v = 2*gy (0.5 folded into mag)
    const float uu[4] = {cur.y - lf, cur.z - cur.x, cur.w - cur.y, rt - cur.z};
    const float vv[4] = {dn.x - up.x, dn.y - up.y, dn.z - up.z, dn.w - up.w};

    __syncthreads();   // zero-fill visible before scatter

    {
        const int base2 = (r * 32 + x0) * 2;
        char* angb = reinterpret_cast<char*>(ang);
        #pragma unroll
        for (int i = 0; i < 4; ++i) {
            const float u = uu[i], v = vv[i];
            const float gw = gxs[i] * gyw;
            const float m2 = fmaf(u, u, v * v);
            const float mag = __builtin_amdgcn_sqrtf(fmaf(m2, 0.25f, EPS)) * gw;

            // octant-direct soft binning (bins are exactly pi/4 wide)
            const float gxe = u + 2e-10f;
            const float ax = fabsf(gxe), ay = fabsf(v);
            const float mx = fmaxf(ax, ay), mn = fminf(ax, ay);
            const float t = mn * __builtin_amdgcn_rcpf(fmaxf(mx, 1e-35f));
            const float s = t * t;
            float pl = fmaf(s, -0.1083947f, 0.2293632f);   // 4-term, pre-scaled by 4/pi
            pl = fmaf(s, pl, -0.4205503f);
            pl = fmaf(s, pl, 1.2730689f);
            const float p  = t * pl;                       // in-octant fraction [0,1]
            const float pc = 1.0f - p;

            const int ssw = (ay > ax);
            const int sx  = (gxe < 0.0f);
            const int sy  = (v < 0.0f);
            const int bit0 = ssw ^ sx;
            const int oct  = ((sx << 1) | bit0) ^ (sy ? 7 : 0);   // = bin0
            const float w1 = (bit0 ^ sy) ? pc : p;                // |p - parity|
            const float m1 = w1 * mag;
            const float m0 = mag - m1;

            const __hip_bfloat162 hh = __float22bfloat162_rn(make_float2(m0, m1));
            unsigned int pk; __builtin_memcpy(&pk, &hh, 4);
            const int t0 = oct << 11;
            const int t1 = (t0 + 2048) & 0x3FFF;
            *reinterpret_cast<unsigned short*>(angb + t0 + base2 + 2 * i) =
                (unsigned short)pk;
            *reinterpret_cast<unsigned short*>(angb + t1 + base2 + 2 * i) =
                (unsigned short)(pk >> 16);
        }
    }
    __syncthreads();

    // ---- GEMM1 (MFMA): x-pooling. A = ang (256x32), B^T = WXT (16x32) ----
    float* r2f = reinterpret_cast<float*>(ang);   // union: overwritten AFTER afrag preload
    {
        const int l = tid & 63, w = tid >> 6, g = l >> 4, n = l & 15;
        const bf16x8 bfrag = *reinterpret_cast<const bf16x8*>(WXT.v + n * 32 + g * 8);
        const bf16x8 af0 = *reinterpret_cast<const bf16x8*>(ang + ((w * 4 + 0) * 16 + n) * 32 + g * 8);
        const bf16x8 af1 = *reinterpret_cast<const bf16x8*>(ang + ((w * 4 + 1) * 16 + n) * 32 + g * 8);
        const bf16x8 af2 = *reinterpret_cast<const bf16x8*>(ang + ((w * 4 + 2) * 16 + n) * 32 + g * 8);
        const bf16x8 af3 = *reinterpret_cast<const bf16x8*>(ang + ((w * 4 + 3) * 16 + n) * 32 + g * 8);
        __syncthreads();   // all LDS reads of ang complete before r2f overwrites it

        const f32x4 zacc = {0.f, 0.f, 0.f, 0.f};
        #pragma unroll
        for (int tt = 0; tt < 4; ++tt) {
            const bf16x8 afrag = (tt == 0) ? af0 : (tt == 1) ? af1 : (tt == 2) ? af2 : af3;
            const f32x4 acc = __builtin_amdgcn_mfma_f32_16x16x32_bf16(afrag, bfrag, zacc, 0, 0, 0);
            if (n < 4) {
                // C layout: row = T*16 + 4g + reg, col = n (=ox)
                const int row = (w * 4 + tt) * 16 + 4 * g;
                const int a = row >> 5, y0 = row & 31;
                *reinterpret_cast<float4*>(r2f + (a * 4 + n) * R2S + y0) =
                    make_float4(acc[0], acc[1], acc[2], acc[3]);
            }
        }
    }
    __syncthreads();

    // ---- phase 2: y-pooling (VALU) ----
    float v = 0.0f;
    if (tid < 128) {
        const int a = tid >> 4, oy = (tid >> 2) & 3, ox = tid & 3;
        const float* rp = r2f + (a * 4 + ox) * R2S;
        const int y0 = oy * 8 - 3;
        #pragma unroll
        for (int k = 0; k < 12; ++k) {
            const float wk = 6.0f - fabsf((float)k - 5.5f);   // compile-time
            const int yy = y0 + k;
            const int yc = (yy < 0) ? 0 : ((yy > 31) ? 31 : yy);
            const float wv = (yy == yc) ? wk : 0.0f;
            v = fmaf(wv, rp[yc], v);
        }
    }

    // ---- norm chain: l2 -> clip(0,0.2) -> l2 -> l1 -> sqrt(+eps) ----
    float red = v * v;
    #pragma unroll
    for (int off = 32; off; off >>= 1) red += __shfl_down(red, off);
    if ((tid & 63) == 0 && tid < 128) scratch[tid >> 6] = red;
    __syncthreads();
    float s2 = scratch[0] + scratch[1];
    v = v / fmaxf(__builtin_amdgcn_sqrtf(s2), 1e-12f);
    v = fminf(fmaxf(v, 0.0f), 0.2f);

    red = v * v;
    #pragma unroll
    for (int off = 32; off; off >>= 1) red += __shfl_down(red, off);
    if ((tid & 63) == 0 && tid < 128) scratch[2 + (tid >> 6)] = red;
    __syncthreads();
    float s2b = scratch[2] + scratch[3];
    v = v / fmaxf(__builtin_amdgcn_sqrtf(s2b), 1e-12f);

    red = v;
    #pragma unroll
    for (int off = 32; off; off >>= 1) red += __shfl_down(red, off);
    if ((tid & 63) == 0 && tid < 128) scratch[4 + (tid >> 6)] = red;
    __syncthreads();
    float s1 = scratch[4] + scratch[5];
    v = __builtin_amdgcn_sqrtf(v / fmaxf(s1, 1e-12f) + EPS);

    if (tid < 128) out[(size_t)b * 128 + tid] = v;
}

extern "C" void kernel_launch(void* const* d_in, const int* in_sizes, int n_in,
                              void* d_out, int out_size, void* d_ws, size_t ws_size,
                              hipStream_t stream) {
    const float* in = (const float*)d_in[0];
    float* out = (float*)d_out;
    const int batch = in_sizes[0] / 1024;   // 32*32 per patch
    sift_desc_kernel<<<batch, 256, 0, stream>>>(in, out);
}

// Round 9
// 33.114 us; speedup vs baseline: 1.2815x; 1.2708x over previous
//
#include <hip/hip_runtime.h>
#include <hip/hip_fp16.h>
#include <math.h>

typedef __attribute__((ext_vector_type(8))) _Float16 f16x8;
typedef __attribute__((ext_vector_type(4))) float f32x4;
typedef __attribute__((ext_vector_type(2))) float f32x2;

// constexpr float -> fp16 bits (positive normals + zero only; exact for our values)
static constexpr unsigned short f2h(float f) {
    if (f == 0.0f) return 0;
    unsigned u = __builtin_bit_cast(unsigned, f);
    int e = (int)((u >> 23) & 0xff) - 127 + 15;
    unsigned m = (u >> 13) & 0x3ff;
    return (unsigned short)((e << 10) | m);
}

// triangular pooling table WXT[n][k] (fp16 bits); conv ksize=12, stride=8, pad=3
struct alignas(16) WxTbl { unsigned short v[16 * 32]; };
static constexpr WxTbl gen_wx() {
    WxTbl t{};
    for (int n = 0; n < 16; ++n)
        for (int k = 0; k < 32; ++k) {
            float w = 0.0f;
            if (n < 4) {
                int kk = k - 8 * n + 3;
                if (kk >= 0 && kk < 12) {
                    float d = (float)kk - 5.5f; if (d < 0) d = -d;
                    w = 6.0f - d;               // unnormalized tri; scale cancels in l2norm
                }
            }
            t.v[n * 32 + k] = f2h(w);
        }
    return t;
}
__device__ const WxTbl WXT = gen_wx();

// separable gaussian table G[i] = exp(-(i-15.5)^2/1024), constexpr Taylor
struct alignas(16) GTbl { float v[32]; };
static constexpr GTbl gen_g() {
    GTbl t{};
    for (int i = 0; i < 32; ++i) {
        double x = -((i - 15.5) * (i - 15.5)) / 1024.0;
        double s = 1.0, term = 1.0;
        for (int k = 1; k < 16; ++k) { term *= x / k; s += term; }
        t.v[i] = (float)s;
    }
    return t;
}
__device__ const GTbl GT = gen_g();

__global__ __launch_bounds__(256, 8) void sift_desc_kernel(
        const float* __restrict__ in, float* __restrict__ out) {
    // 16 KB. Phase A: ang[bin*32+y][x] fp16. Phase B: front 2 KB reused as fp16 r2[32][32].
    __shared__ __align__(16) unsigned short ang[8192];

    const int b = blockIdx.x, tid = threadIdx.x;
    constexpr float EPS = 1e-10f;

    // zero-fill ang
    {
        const float4 z = make_float4(0.f, 0.f, 0.f, 0.f);
        float4* az = reinterpret_cast<float4*>(ang);
        az[tid] = z; az[tid + 256] = z; az[tid + 512] = z; az[tid + 768] = z;
    }

    // ---- phase 0: gradients from global (L3-resident) ----
    const int r  = tid >> 3;          // row 0..31
    const int sg = tid & 7;           // segment 0..7
    const int x0 = sg * 4;
    const float* gp = in + (size_t)b * 1024;
    const float4 cur = *reinterpret_cast<const float4*>(gp + r * 32 + x0);
    const int rup = (r > 0) ? r - 1 : 0, rdn = (r < 31) ? r + 1 : 31;
    const float4 up = *reinterpret_cast<const float4*>(gp + rup * 32 + x0);
    const float4 dn = *reinterpret_cast<const float4*>(gp + rdn * 32 + x0);
    const float gyw = GT.v[r];
    const float4 gxw4 = *reinterpret_cast<const float4*>(GT.v + x0);

    const float lfs = __shfl_up(cur.w, 1);
    const float rts = __shfl_down(cur.x, 1);
    const float lf = (sg == 0) ? cur.x : lfs;   // replicate-pad at x=0
    const float rt = (sg == 7) ? cur.w : rts;   // replicate-pad at x=31

    // u = 2*gx, v = 2*gy (0.5 folded into mag), as pixel pairs for packed fp32
    const f32x2 uP[2] = {{cur.y - lf, cur.z - cur.x}, {cur.w - cur.y, rt - cur.z}};
    const f32x2 vP[2] = {{dn.x - up.x, dn.y - up.y}, {dn.z - up.z, dn.w - up.w}};
    const f32x2 gP[2] = {{gxw4.x, gxw4.y}, {gxw4.z, gxw4.w}};

    __syncthreads();   // barrier 1: zero-fill visible before scatter

    // ---- weighted magnitude + octant soft-bin scatter (packed math) ----
    {
        const int base2 = (r * 32 + x0) * 2;
        char* angb = reinterpret_cast<char*>(ang);
        #pragma unroll
        for (int h = 0; h < 2; ++h) {
            const f32x2 u = uP[h], v = vP[h];
            const f32x2 gw = gP[h] * gyw;                       // pk_mul
            const f32x2 m2 = u * u + v * v;                     // pk_mul + pk_fma
            const f32x2 marg = m2 * 0.25f + EPS;                // pk_fma
            const f32x2 sq = {__builtin_amdgcn_sqrtf(marg.x),
                              __builtin_amdgcn_sqrtf(marg.y)};
            const f32x2 mag = sq * gw;                          // pk_mul

            const f32x2 gxe = u + 2e-10f;                       // pk_add
            const f32x2 ax = __builtin_elementwise_abs(gxe);
            const f32x2 ay = __builtin_elementwise_abs(v);
            const f32x2 mx = __builtin_elementwise_max(
                __builtin_elementwise_max(ax, ay), (f32x2)1e-35f);
            const f32x2 mn = __builtin_elementwise_min(ax, ay);
            const f32x2 rc = {__builtin_amdgcn_rcpf(mx.x),
                              __builtin_amdgcn_rcpf(mx.y)};
            const f32x2 t = mn * rc;                            // pk_mul
            const f32x2 s = t * t;                              // pk_mul
            f32x2 pl = s * (-0.1083947f) + 0.2293632f;          // pre-scaled by 4/pi
            pl = s * pl + (-0.4205503f);
            pl = s * pl + 1.2730689f;
            const f32x2 p  = t * pl;                            // in-octant fraction
            const f32x2 pc = 1.0f - p;

            #pragma unroll
            for (int e = 0; e < 2; ++e) {
                const int ssw = (ay[e] > ax[e]);
                const int sx  = (gxe[e] < 0.0f);
                const int sy  = (v[e] < 0.0f);
                const int bit0 = ssw ^ sx;
                const int oct  = ((sx << 1) | bit0) ^ (sy ? 7 : 0);   // = bin0
                const float w1 = (bit0 ^ sy) ? pc[e] : p[e];
                const float m1 = w1 * mag[e];
                const float m0 = mag[e] - m1;

                const __half2 hh = __float22half2_rn(make_float2(m0, m1));
                unsigned int pk; __builtin_memcpy(&pk, &hh, 4);
                const int t0 = oct << 11;
                const int t1 = (t0 + 2048) & 0x3FFF;
                const int off = base2 + 2 * (2 * h + e);
                *reinterpret_cast<unsigned short*>(angb + t0 + off) = (unsigned short)pk;
                *reinterpret_cast<unsigned short*>(angb + t1 + off) = (unsigned short)(pk >> 16);
            }
        }
    }
    __syncthreads();   // barrier 2: scatter complete

    // ---- GEMM1 (MFMA fp16): x-pooling. A = ang (256x32), B^T = WXT (16x32) ----
    const int l = tid & 63, w = tid >> 6, g = l >> 4, n = l & 15;
    const f16x8 bfrag = *reinterpret_cast<const f16x8*>(WXT.v + n * 32 + g * 8);
    unsigned short* r2 = ang;   // union: front 2 KB, overwritten AFTER afrag preload
    {
        const f16x8 af0 = *reinterpret_cast<const f16x8*>(ang + ((w * 4 + 0) * 16 + n) * 32 + g * 8);
        const f16x8 af1 = *reinterpret_cast<const f16x8*>(ang + ((w * 4 + 1) * 16 + n) * 32 + g * 8);
        const f16x8 af2 = *reinterpret_cast<const f16x8*>(ang + ((w * 4 + 2) * 16 + n) * 32 + g * 8);
        const f16x8 af3 = *reinterpret_cast<const f16x8*>(ang + ((w * 4 + 3) * 16 + n) * 32 + g * 8);
        __syncthreads();   // barrier 3: all ang reads done before r2 overwrite

        const f32x4 zacc = {0.f, 0.f, 0.f, 0.f};
        #pragma unroll
        for (int tt = 0; tt < 4; ++tt) {
            const f16x8 afrag = (tt == 0) ? af0 : (tt == 1) ? af1 : (tt == 2) ? af2 : af3;
            const f32x4 acc = __builtin_amdgcn_mfma_f32_16x16x32_f16(afrag, bfrag, zacc, 0, 0, 0);
            if (n < 4) {
                // C layout: row = T*16 + 4g + reg (= a*32 + y), col = n (= ox)
                const int row = (w * 4 + tt) * 16 + 4 * g;
                const int a = row >> 5, y0 = row & 31;
                const __half2 p01 = __float22half2_rn(make_float2(acc[0], acc[1]));
                const __half2 p23 = __float22half2_rn(make_float2(acc[2], acc[3]));
                unsigned int lo, hi;
                __builtin_memcpy(&lo, &p01, 4);
                __builtin_memcpy(&hi, &p23, 4);
                // r2[row2 = a*4+ox][y], fp16, row stride 32
                *reinterpret_cast<uint2*>(r2 + (a * 4 + n) * 32 + y0) = make_uint2(lo, hi);
            }
        }
    }
    __syncthreads();   // barrier 4: r2 complete
    if (tid >= 64) return;   // waves 1-3 done

    // ---- GEMM2 (wave 0): y-pooling. A = r2 (32x32), B^T = WXT again (wy == wx) ----
    const f16x8 fa0 = *reinterpret_cast<const f16x8*>(r2 + (n)      * 32 + g * 8);
    const f16x8 fa1 = *reinterpret_cast<const f16x8*>(r2 + (16 + n) * 32 + g * 8);
    const f32x4 zacc = {0.f, 0.f, 0.f, 0.f};
    const f32x4 d0 = __builtin_amdgcn_mfma_f32_16x16x32_f16(fa0, bfrag, zacc, 0, 0, 0);
    const f32x4 d1 = __builtin_amdgcn_mfma_f32_16x16x32_f16(fa1, bfrag, zacc, 0, 0, 0);

    // lane (g,n), reg rr: d0 -> desc[a=g][oy=n][ox=rr], d1 -> desc[a=4+g][oy=n][ox=rr]
    const bool act = (n < 4);
    float q0 = act ? d0[0] : 0.f, q1 = act ? d0[1] : 0.f;
    float q2 = act ? d0[2] : 0.f, q3 = act ? d0[3] : 0.f;
    float q4 = act ? d1[0] : 0.f, q5 = act ? d1[1] : 0.f;
    float q6 = act ? d1[2] : 0.f, q7 = act ? d1[3] : 0.f;

    // ---- norm chain in-wave: l2 -> clip(0,0.2) -> l2 -> l1 -> sqrt(+eps) ----
    float ss = q0*q0 + q1*q1 + q2*q2 + q3*q3 + q4*q4 + q5*q5 + q6*q6 + q7*q7;
    #pragma unroll
    for (int off = 32; off; off >>= 1) ss += __shfl_xor(ss, off);
    const float inv = __builtin_amdgcn_rcpf(fmaxf(__builtin_amdgcn_sqrtf(ss), 1e-12f));
    q0 = fminf(q0 * inv, 0.2f); q1 = fminf(q1 * inv, 0.2f);
    q2 = fminf(q2 * inv, 0.2f); q3 = fminf(q3 * inv, 0.2f);
    q4 = fminf(q4 * inv, 0.2f); q5 = fminf(q5 * inv, 0.2f);
    q6 = fminf(q6 * inv, 0.2f); q7 = fminf(q7 * inv, 0.2f);

    float ss2 = q0*q0 + q1*q1 + q2*q2 + q3*q3 + q4*q4 + q5*q5 + q6*q6 + q7*q7;
    #pragma unroll
    for (int off = 32; off; off >>= 1) ss2 += __shfl_xor(ss2, off);
    const float inv2 = __builtin_amdgcn_rcpf(fmaxf(__builtin_amdgcn_sqrtf(ss2), 1e-12f));
    q0 *= inv2; q1 *= inv2; q2 *= inv2; q3 *= inv2;
    q4 *= inv2; q5 *= inv2; q6 *= inv2; q7 *= inv2;

    float s1 = q0 + q1 + q2 + q3 + q4 + q5 + q6 + q7;
    #pragma unroll
    for (int off = 32; off; off >>= 1) s1 += __shfl_xor(s1, off);
    const float inv1 = __builtin_amdgcn_rcpf(fmaxf(s1, 1e-12f));
    q0 = __builtin_amdgcn_sqrtf(fmaf(q0, inv1, EPS));
    q1 = __builtin_amdgcn_sqrtf(fmaf(q1, inv1, EPS));
    q2 = __builtin_amdgcn_sqrtf(fmaf(q2, inv1, EPS));
    q3 = __builtin_amdgcn_sqrtf(fmaf(q3, inv1, EPS));
    q4 = __builtin_amdgcn_sqrtf(fmaf(q4, inv1, EPS));
    q5 = __builtin_amdgcn_sqrtf(fmaf(q5, inv1, EPS));
    q6 = __builtin_amdgcn_sqrtf(fmaf(q6, inv1, EPS));
    q7 = __builtin_amdgcn_sqrtf(fmaf(q7, inv1, EPS));

    if (act) {
        // out idx = a*16 + oy*4 + ox = (d0) 16g + 4n + rr, (d1) 64 + 16g + 4n + rr
        float* op = out + (size_t)b * 128 + 16 * g + 4 * n;
        *reinterpret_cast<float4*>(op)      = make_float4(q0, q1, q2, q3);
        *reinterpret_cast<float4*>(op + 64) = make_float4(q4, q5, q6, q7);
    }
}

extern "C" void kernel_launch(void* const* d_in, const int* in_sizes, int n_in,
                              void* d_out, int out_size, void* d_ws, size_t ws_size,
                              hipStream_t stream) {
    const float* in = (const float*)d_in[0];
    float* out = (float*)d_out;
    const int batch = in_sizes[0] / 1024;   // 32*32 per patch
    sift_desc_kernel<<<batch, 256, 0, stream>>>(in, out);
}